// Round 1
// baseline (7244.912 us; speedup 1.0000x reference)
//
#include <hip/hip_runtime.h>
#include <cmath>

// Problem constants (reference: n = m = 8192, d = 64, reg = 0.05, 20 iters)
#define NPTS 8192
#define DIM  64

constexpr int TJ    = 128;  // XQ rows per LDS tile
constexpr int TILES = 4;    // tiles per block => 512 cols per block
constexpr int BLK   = 256;  // threads per block (one row of C per thread)

// ---------------------------------------------------------------------------
// setup: zero v, saccU, scalars (cmax bits, Kv, Ku), and the output
// ---------------------------------------------------------------------------
__global__ void setup_kernel(float* __restrict__ v, float* __restrict__ saccU,
                             float* __restrict__ scal, float* __restrict__ out) {
  int i = blockIdx.x * blockDim.x + threadIdx.x;
  if (i < NPTS) { v[i] = 0.0f; saccU[i] = 0.0f; }
  if (i == 0) {
    ((unsigned int*)scal)[0] = 0u;  // cmax (float bits, values >= 0)
    scal[1] = 0.0f;                 // Kv
    scal[2] = 0.0f;                 // Ku
    out[0]  = 0.0f;
  }
}

// ---------------------------------------------------------------------------
// squared row norms: one 64-lane wave per row
// ---------------------------------------------------------------------------
__global__ void sqnorm_kernel(const float* __restrict__ X, float* __restrict__ out) {
  int gid  = blockIdx.x * blockDim.x + threadIdx.x;
  int row  = gid >> 6;
  int lane = threadIdx.x & 63;
  float x = X[row * DIM + lane];
  float s = x * x;
  for (int off = 32; off; off >>= 1) s += __shfl_down(s, off, 64);
  if (lane == 0) out[row] = s;
}

// ---------------------------------------------------------------------------
// The workhorse: one full sweep over a (256-row x 512-col) block of C,
// recomputing d2 = max(x2_i + y2_j - 2*dot(XP_i, XQ_j), 0) on the fly.
// MODE 0: block max of d2       -> atomicMax(uint) on outScalar
// MODE 1: s_i += exp(-d2*invC + (w_j - K))  -> atomicAdd(outSacc[i])
// MODE 2: s += d2 * exp(-d2*invC + u_i + w_j) -> atomicAdd(outScalar)
// ---------------------------------------------------------------------------
template <int MODE>
__global__ __launch_bounds__(BLK) void pass_kernel(
    const float4* __restrict__ P, const float4* __restrict__ Q,
    const float* __restrict__ p2, const float* __restrict__ q2,
    const float* __restrict__ w, const float* __restrict__ Kp,
    const float* __restrict__ uarr, const unsigned int* __restrict__ cmaxBits,
    float* __restrict__ outSacc, float* __restrict__ outScalar) {
  __shared__ float4 sQ[TJ * 16];  // 32 KB tile of XQ rows
  __shared__ float  sY2[TJ];
  __shared__ float  sW[TJ];
  __shared__ float  red[BLK];

  const int t      = threadIdx.x;
  const int i      = blockIdx.x * BLK + t;           // row of C owned by thread
  const int j0base = blockIdx.y * (TJ * TILES);

  // this thread's XP row in registers (16 float4 = 64 floats)
  float4 xp[16];
  const float4* Prow = P + (size_t)i * 16;
#pragma unroll
  for (int c = 0; c < 16; ++c) xp[c] = Prow[c];
  const float x2i = p2[i];

  float invC = 0.0f;
  if constexpr (MODE != 0) {
    float cmax = __uint_as_float(*cmaxBits);
    invC = 1.0f / (cmax * 0.05f);  // 1 / (Cmax * reg)
  }
  float K = 0.0f;
  if constexpr (MODE == 1) K = *Kp;
  float ui = 0.0f;
  if constexpr (MODE == 2) ui = uarr[i];

  float acc = 0.0f;  // running sum (modes 1,2) or running max (mode 0)

  for (int tile = 0; tile < TILES; ++tile) {
    const int j0 = j0base + tile * TJ;
    __syncthreads();  // protect previous tile's LDS from overwrite
    {
      const float4* Qbase = Q + (size_t)j0 * 16;
#pragma unroll
      for (int r = 0; r < 8; ++r) sQ[r * BLK + t] = Qbase[r * BLK + t];
      if (t < TJ) {
        sY2[t] = q2[j0 + t];
        if constexpr (MODE == 1) sW[t] = w[j0 + t] - K;
        else if constexpr (MODE == 2) sW[t] = w[j0 + t];
        else sW[t] = 0.0f;
      }
    }
    __syncthreads();

    for (int jj = 0; jj < TJ; ++jj) {
      float ax = 0.f, ay = 0.f, az = 0.f, aw = 0.f;
#pragma unroll
      for (int c = 0; c < 16; ++c) {
        float4 q = sQ[jj * 16 + c];  // wave-uniform address -> LDS broadcast
        ax = fmaf(xp[c].x, q.x, ax);
        ay = fmaf(xp[c].y, q.y, ay);
        az = fmaf(xp[c].z, q.z, az);
        aw = fmaf(xp[c].w, q.w, aw);
      }
      float dot = (ax + ay) + (az + aw);
      float d2  = x2i + sY2[jj] - 2.0f * dot;
      d2 = fmaxf(d2, 0.0f);
      if constexpr (MODE == 0) {
        acc = fmaxf(acc, d2);
      } else if constexpr (MODE == 1) {
        acc += __expf(fmaf(-invC, d2, sW[jj]));
      } else {
        acc += d2 * __expf(fmaf(-invC, d2, ui + sW[jj]));
      }
    }
  }

  if constexpr (MODE == 1) {
    atomicAdd(&outSacc[i], acc);  // coalesced; 16 col-chunk blocks per row
  } else {
    __syncthreads();
    red[t] = acc;
    __syncthreads();
    for (int off = BLK / 2; off; off >>= 1) {
      if (t < off) {
        if constexpr (MODE == 0) red[t] = fmaxf(red[t], red[t + off]);
        else red[t] = red[t] + red[t + off];
      }
      __syncthreads();
    }
    if (t == 0) {
      if constexpr (MODE == 0)
        atomicMax((unsigned int*)outScalar, __float_as_uint(red[0]));
      else
        atomicAdd(outScalar, red[0]);
    }
  }
}

// ---------------------------------------------------------------------------
// finalize: pot[idx] = la - Ks - log(sacc[idx]); Kout = max(pot); zero other sacc
// single block, 1024 threads, 8 elements each
// ---------------------------------------------------------------------------
__global__ __launch_bounds__(1024) void finalize_kernel(
    const float* __restrict__ sacc, float* __restrict__ pot,
    float* __restrict__ Kout, float* __restrict__ zeroBuf,
    const float* __restrict__ Kin, float la) {
  __shared__ float red[1024];
  const int t = threadIdx.x;
  const float Ks = *Kin;
  float lmax = -INFINITY;
#pragma unroll
  for (int r = 0; r < 8; ++r) {
    int idx = r * 1024 + t;
    float val = la - Ks - logf(sacc[idx]);
    pot[idx] = val;
    lmax = fmaxf(lmax, val);
    zeroBuf[idx] = 0.0f;
  }
  red[t] = lmax;
  __syncthreads();
  for (int off = 512; off; off >>= 1) {
    if (t < off) red[t] = fmaxf(red[t], red[t + off]);
    __syncthreads();
  }
  if (t == 0) *Kout = red[0];
}

// ---------------------------------------------------------------------------
extern "C" void kernel_launch(void* const* d_in, const int* in_sizes, int n_in,
                              void* d_out, int out_size, void* d_ws, size_t ws_size,
                              hipStream_t stream) {
  (void)in_sizes; (void)n_in; (void)out_size; (void)ws_size;
  const float* XP = (const float*)d_in[0];
  const float* XQ = (const float*)d_in[1];
  float* out = (float*)d_out;

  float* ws    = (float*)d_ws;
  float* x2    = ws;            // 8192
  float* y2    = ws + 8192;     // 8192
  float* u     = ws + 16384;    // 8192
  float* v     = ws + 24576;    // 8192
  float* saccU = ws + 32768;    // 8192
  float* saccV = ws + 40960;    // 8192
  float* scal  = ws + 49152;    // [0]=cmax bits, [1]=Kv, [2]=Ku

  const float LA = -logf(8192.0f);
  const float LB = LA;

  setup_kernel<<<NPTS / 256, 256, 0, stream>>>(v, saccU, scal, out);
  sqnorm_kernel<<<NPTS * DIM / 256, 256, 0, stream>>>(XP, x2);
  sqnorm_kernel<<<NPTS * DIM / 256, 256, 0, stream>>>(XQ, y2);

  dim3 grid(NPTS / BLK, NPTS / (TJ * TILES));  // (32, 16)

  // Cmax = max over all pairs of clamped d2
  pass_kernel<0><<<grid, BLK, 0, stream>>>(
      (const float4*)XP, (const float4*)XQ, x2, y2,
      nullptr, nullptr, nullptr, nullptr, nullptr, scal);

  for (int it = 0; it < 20; ++it) {
    // u = la - lse_j(M + v): shift by Kv = max(v)
    pass_kernel<1><<<grid, BLK, 0, stream>>>(
        (const float4*)XP, (const float4*)XQ, x2, y2,
        v, scal + 1, nullptr, (const unsigned int*)scal, saccU, nullptr);
    finalize_kernel<<<1, 1024, 0, stream>>>(saccU, u, scal + 2, saccV, scal + 1, LA);
    // v = lb - lse_i(M + u): shift by Ku = max(u); swap P/Q roles
    pass_kernel<1><<<grid, BLK, 0, stream>>>(
        (const float4*)XQ, (const float4*)XP, y2, x2,
        u, scal + 2, nullptr, (const unsigned int*)scal, saccV, nullptr);
    finalize_kernel<<<1, 1024, 0, stream>>>(saccV, v, scal + 1, saccU, scal + 2, LB);
  }

  // result = sum_ij d2_ij * exp(-d2_ij*invC + u_i + v_j)
  pass_kernel<2><<<grid, BLK, 0, stream>>>(
      (const float4*)XP, (const float4*)XQ, x2, y2,
      v, nullptr, u, (const unsigned int*)scal, nullptr, out);
}

// Round 2
// 1792.028 us; speedup vs baseline: 4.0429x; 4.0429x over previous
//
#include <hip/hip_runtime.h>
#include <cmath>

// n = m = 8192, d = 64, reg = 0.05, 20 Sinkhorn iterations
#define NPTS 8192
#define DIM  64
#define LOG2E 1.4426950408889634f

typedef short s16x8  __attribute__((ext_vector_type(8)));   // 8 bf16 (4 VGPRs)
typedef float f32x16 __attribute__((ext_vector_type(16)));  // MFMA 32x32 acc

// ---- bf16 helpers (RTNE) --------------------------------------------------
__device__ __forceinline__ unsigned short f2bf(float x) {
  unsigned u = __float_as_uint(x);
  return (unsigned short)((u + 0x7FFFu + ((u >> 16) & 1u)) >> 16);
}
__device__ __forceinline__ float bf2f(unsigned short b) {
  return __uint_as_float(((unsigned)b) << 16);
}

// ---------------------------------------------------------------------------
__global__ void setup_kernel(float* __restrict__ v, float* __restrict__ saccU,
                             float* __restrict__ scal, float* __restrict__ out) {
  int i = blockIdx.x * 256 + threadIdx.x;
  v[i] = 0.0f; saccU[i] = 0.0f;
  if (i == 0) { ((unsigned*)scal)[0] = 0u; out[0] = 0.0f; }
}

// split fp32 -> bf16 hi + bf16 lo for both point clouds (1 MB each array)
__global__ void prep_kernel(const float* __restrict__ XP, const float* __restrict__ XQ,
                            unsigned short* __restrict__ Phi, unsigned short* __restrict__ Plo,
                            unsigned short* __restrict__ Qhi, unsigned short* __restrict__ Qlo) {
  int i = blockIdx.x * 256 + threadIdx.x;  // 0 .. 8192*64-1
  float x = XP[i];
  unsigned short h = f2bf(x);
  Phi[i] = h; Plo[i] = f2bf(x - bf2f(h));
  float y = XQ[i];
  h = f2bf(y);
  Qhi[i] = h; Qlo[i] = f2bf(y - bf2f(h));
}

// squared row norms from the exact fp32 data: one 64-lane wave per row
__global__ void sqnorm_kernel(const float* __restrict__ X, float* __restrict__ out) {
  int gid  = blockIdx.x * blockDim.x + threadIdx.x;
  int row  = gid >> 6;
  int lane = threadIdx.x & 63;
  float x = X[row * DIM + lane];
  float s = x * x;
  for (int off = 32; off; off >>= 1) s += __shfl_down(s, off, 64);
  if (lane == 0) out[row] = s;
}

// ---------------------------------------------------------------------------
// MFMA sweep over a 128x256 tile of the pair matrix. dot = Ahi.Bhi + Alo.Bhi.
// C/D layout (m74/m101): col = lane&31, row = (reg&3) + 8*(reg>>2) + 4*(lane>>5)
// MODE 0: cmax = max d2                    -> atomicMax(uint) outScalar
// MODE 1: sacc_row += 2^(C2L*dot + base_j) -> atomicAdd outSacc   (x2 factored out)
// MODE 2: out += d2 * 2^(C2L*dot + bu_i + base_j) -> atomicAdd outScalar
// ---------------------------------------------------------------------------
template <int MODE>
__global__ __launch_bounds__(256) void pass_kernel(
    const unsigned short* __restrict__ Ahi, const unsigned short* __restrict__ Alo,
    const unsigned short* __restrict__ Bhi,
    const float* __restrict__ x2row,   // row-side squared norms (modes 0,2)
    const float* __restrict__ y2col,   // col-side squared norms
    const float* __restrict__ wcol,    // col potential (modes 1,2)
    const float* __restrict__ urow,    // row potential (mode 2)
    const unsigned* __restrict__ cmaxBits,
    float* __restrict__ outSacc, float* __restrict__ outScalar) {
  __shared__ short sB[256 * 64];   // 32 KB, xor-swizzled 16B chunks
  __shared__ float sBase2[256];
  __shared__ float sY2[256];
  __shared__ float sX2[128];
  __shared__ float sU2[128];

  const int t  = threadIdx.x;
  const int w  = t >> 6;       // wave 0..3 -> rows w*32..w*32+31
  const int l  = t & 63;
  const int g  = l >> 5;       // lane group
  const int ln = l & 31;
  const int i0 = blockIdx.x * 128;
  const int j0 = blockIdx.y * 256;

  float invC = 0.0f, C2L = 0.0f;
  if constexpr (MODE != 0) {
    float cmax = __uint_as_float(*cmaxBits);
    invC = 1.0f / (0.05f * cmax);
    C2L  = 2.0f * invC * LOG2E;
  }

  // A fragments: lane holds A[m = ln][k = g*8 + j] for each 16-wide k step
  s16x8 a_hi[4], a_lo[4];
  {
    const unsigned short* pa = Ahi + (size_t)(i0 + w * 32 + ln) * 64 + g * 8;
    const unsigned short* pb = Alo + (size_t)(i0 + w * 32 + ln) * 64 + g * 8;
#pragma unroll
    for (int ks = 0; ks < 4; ++ks) {
      a_hi[ks] = *(const s16x8*)(pa + ks * 16);
      a_lo[ks] = *(const s16x8*)(pb + ks * 16);
    }
  }

  // stage B tile (256 XQ-rows x 64 feats, bf16 hi) with xor swizzle
  {
    const int4* src = (const int4*)(Bhi + (size_t)j0 * 64);
    int4* dst = (int4*)sB;
#pragma unroll
    for (int kk = 0; kk < 8; ++kk) {
      int idx = t + kk * 256;          // 0..2047 int4s
      int row = idx >> 3, c = idx & 7;
      dst[row * 8 + (c ^ (row & 7))] = src[idx];
    }
  }
  {
    float y2v = y2col[j0 + t];
    if constexpr (MODE != 0) sBase2[t] = (wcol[j0 + t] - invC * y2v) * LOG2E;
    if constexpr (MODE != 1) sY2[t] = y2v;
  }
  if constexpr (MODE != 1) {
    if (t < 128) {
      float xv = x2row[i0 + t];
      sX2[t] = xv;
      if constexpr (MODE == 2) sU2[t] = (urow[i0 + t] - invC * xv) * LOG2E;
    }
  }
  __syncthreads();

  float x2r[16], u2r[16];
  if constexpr (MODE != 1) {
#pragma unroll
    for (int r = 0; r < 16; ++r) {
      int ri = w * 32 + (r & 3) + 8 * (r >> 2) + 4 * g;
      x2r[r] = sX2[ri];
      if constexpr (MODE == 2) u2r[r] = sU2[ri];
    }
  }

  float racc[16];
#pragma unroll
  for (int r = 0; r < 16; ++r) racc[r] = 0.0f;
  float accS = 0.0f;
  const int swz = l & 7;

  for (int ct = 0; ct < 8; ++ct) {
    const int n = ct * 32 + ln;
    s16x8 b[4];
#pragma unroll
    for (int ks = 0; ks < 4; ++ks) {
      int chunk = (ks * 2 + g) ^ swz;   // conflict-free: 8 lanes cover 32 banks
      b[ks] = *(const s16x8*)(sB + n * 64 + chunk * 8);
    }
    f32x16 acc;
#pragma unroll
    for (int r = 0; r < 16; ++r) acc[r] = 0.0f;
#pragma unroll
    for (int ks = 0; ks < 4; ++ks)
      acc = __builtin_amdgcn_mfma_f32_32x32x16_bf16(a_hi[ks], b[ks], acc, 0, 0, 0);
#pragma unroll
    for (int ks = 0; ks < 4; ++ks)
      acc = __builtin_amdgcn_mfma_f32_32x32x16_bf16(a_lo[ks], b[ks], acc, 0, 0, 0);

    if constexpr (MODE == 1) {
      float bb2 = sBase2[ct * 32 + ln];
#pragma unroll
      for (int r = 0; r < 16; ++r)
        racc[r] += exp2f(fmaf(C2L, acc[r], bb2));
    } else if constexpr (MODE == 0) {
      float y2v = sY2[ct * 32 + ln];
#pragma unroll
      for (int r = 0; r < 16; ++r) {
        float d2 = fmaf(-2.0f, acc[r], x2r[r] + y2v);
        accS = fmaxf(accS, d2);
      }
    } else {
      float y2v = sY2[ct * 32 + ln];
      float bb2 = sBase2[ct * 32 + ln];
#pragma unroll
      for (int r = 0; r < 16; ++r) {
        float d2 = fmaxf(fmaf(-2.0f, acc[r], x2r[r] + y2v), 0.0f);
        float e  = exp2f(fmaf(C2L, acc[r], u2r[r] + bb2));
        accS = fmaf(d2, e, accS);
      }
    }
  }

  if constexpr (MODE == 1) {
#pragma unroll
    for (int r = 0; r < 16; ++r) {
      float s = racc[r];
      s += __shfl_xor(s, 1, 64);
      s += __shfl_xor(s, 2, 64);
      s += __shfl_xor(s, 4, 64);
      s += __shfl_xor(s, 8, 64);
      s += __shfl_xor(s, 16, 64);
      if (ln == 0)
        atomicAdd(&outSacc[i0 + w * 32 + (r & 3) + 8 * (r >> 2) + 4 * g], s);
    }
  } else {
    float s = accS;
    for (int off = 1; off < 64; off <<= 1) {
      float o = __shfl_xor(s, off, 64);
      s = (MODE == 0) ? fmaxf(s, o) : (s + o);
    }
    if (l == 0) {
      if constexpr (MODE == 0)
        atomicMax((unsigned*)outScalar, __float_as_uint(s));
      else
        atomicAdd(outScalar, s);
    }
  }
}

// pot[i] = la - log(sacc[i]) + invC * sqn[i]   (re-applies the factored e^{-invC*x2})
// and zero the other side's accumulator for the next half-iteration
__global__ void finalize_kernel(const float* __restrict__ sacc, float* __restrict__ pot,
                                const float* __restrict__ sqn, float* __restrict__ zeroBuf,
                                const unsigned* __restrict__ cmaxBits, float la) {
  int i = blockIdx.x * 256 + threadIdx.x;
  float invC = 1.0f / (0.05f * __uint_as_float(*cmaxBits));
  pot[i] = la - __logf(sacc[i]) + invC * sqn[i];
  zeroBuf[i] = 0.0f;
}

// ---------------------------------------------------------------------------
extern "C" void kernel_launch(void* const* d_in, const int* in_sizes, int n_in,
                              void* d_out, int out_size, void* d_ws, size_t ws_size,
                              hipStream_t stream) {
  (void)in_sizes; (void)n_in; (void)out_size; (void)ws_size;
  const float* XP = (const float*)d_in[0];
  const float* XQ = (const float*)d_in[1];
  float* out = (float*)d_out;

  float* ws    = (float*)d_ws;
  float* x2    = ws;             // 8192
  float* y2    = ws + 8192;
  float* u     = ws + 16384;
  float* v     = ws + 24576;
  float* saccU = ws + 32768;
  float* saccV = ws + 40960;
  float* scal  = ws + 49152;     // [0] = cmax bits (16 floats reserved)
  unsigned short* Phi = (unsigned short*)(ws + 49168);  // 16B-aligned
  unsigned short* Plo = Phi + (size_t)NPTS * DIM;
  unsigned short* Qhi = Plo + (size_t)NPTS * DIM;
  unsigned short* Qlo = Qhi + (size_t)NPTS * DIM;       // total ws ~4.4 MB

  const float LA = -logf(8192.0f);

  setup_kernel<<<32, 256, 0, stream>>>(v, saccU, scal, out);
  prep_kernel<<<NPTS * DIM / 256, 256, 0, stream>>>(XP, XQ, Phi, Plo, Qhi, Qlo);
  sqnorm_kernel<<<NPTS * DIM / 256, 256, 0, stream>>>(XP, x2);
  sqnorm_kernel<<<NPTS * DIM / 256, 256, 0, stream>>>(XQ, y2);

  dim3 grid(NPTS / 128, NPTS / 256);  // (64, 32)

  // Cmax
  pass_kernel<0><<<grid, 256, 0, stream>>>(
      Phi, Plo, Qhi, x2, y2, nullptr, nullptr, (const unsigned*)scal, nullptr, scal);

  for (int it = 0; it < 20; ++it) {
    // u-update: rows = P, cols = Q
    pass_kernel<1><<<grid, 256, 0, stream>>>(
        Phi, Plo, Qhi, nullptr, y2, v, nullptr, (const unsigned*)scal, saccU, nullptr);
    finalize_kernel<<<32, 256, 0, stream>>>(saccU, u, x2, saccV, (const unsigned*)scal, LA);
    // v-update: rows = Q, cols = P
    pass_kernel<1><<<grid, 256, 0, stream>>>(
        Qhi, Qlo, Phi, nullptr, x2, u, nullptr, (const unsigned*)scal, saccV, nullptr);
    finalize_kernel<<<32, 256, 0, stream>>>(saccV, v, y2, saccU, (const unsigned*)scal, LA);
  }

  // final sum C * plan
  pass_kernel<2><<<grid, 256, 0, stream>>>(
      Phi, Plo, Qhi, x2, y2, v, u, (const unsigned*)scal, nullptr, out);
}

// Round 3
// 1270.165 us; speedup vs baseline: 5.7039x; 1.4109x over previous
//
#include <hip/hip_runtime.h>
#include <cmath>

// n = m = 8192, d = 64, reg = 0.05, 20 Sinkhorn iterations
#define NPTS 8192
#define DIM  64
#define LOG2E 1.4426950408889634f
#define LA2   -13.0f   // log2(1/8192) exactly

typedef short s16x8  __attribute__((ext_vector_type(8)));   // 8 bf16
typedef float f32x16 __attribute__((ext_vector_type(16)));  // MFMA 32x32 acc

#if __has_builtin(__builtin_amdgcn_exp2f)
__device__ __forceinline__ float exp2_fast(float x) { return __builtin_amdgcn_exp2f(x); }
#else
__device__ __forceinline__ float exp2_fast(float x) { return exp2f(x); }
#endif
#if __has_builtin(__builtin_amdgcn_logf)
__device__ __forceinline__ float log2_fast(float x) { return __builtin_amdgcn_logf(x); }
#else
__device__ __forceinline__ float log2_fast(float x) { return log2f(x); }
#endif

__device__ __forceinline__ unsigned short f2bf(float x) {
  unsigned u = __float_as_uint(x);
  return (unsigned short)((u + 0x7FFFu + ((u >> 16) & 1u)) >> 16);
}
__device__ __forceinline__ float bf2f(unsigned short b) {
  return __uint_as_float(((unsigned)b) << 16);
}

// ---------------------------------------------------------------------------
// prep: bf16 hi/lo split + squared row norms for both clouds; init scal/out.
// one 64-lane wave per point row.
// ---------------------------------------------------------------------------
__global__ __launch_bounds__(256) void prep_kernel(
    const float* __restrict__ XP, const float* __restrict__ XQ,
    unsigned short* __restrict__ Phi, unsigned short* __restrict__ Plo,
    unsigned short* __restrict__ Qhi, unsigned short* __restrict__ Qlo,
    float* __restrict__ x2, float* __restrict__ y2,
    float* __restrict__ scal, float* __restrict__ out) {
  int gid  = blockIdx.x * 256 + threadIdx.x;
  int lane = threadIdx.x & 63;
  int row  = gid >> 6;            // 0..16383: P rows then Q rows (wave-uniform)
  int isP  = row < NPTS;
  int r    = row & (NPTS - 1);
  const float* X = isP ? XP : XQ;
  float x = X[r * DIM + lane];
  unsigned short h = f2bf(x);
  (isP ? Phi : Qhi)[r * DIM + lane] = h;
  (isP ? Plo : Qlo)[r * DIM + lane] = f2bf(x - bf2f(h));
  float s = x * x;
  for (int off = 32; off; off >>= 1) s += __shfl_down(s, off, 64);
  if (lane == 0) (isP ? x2 : y2)[r] = s;
  if (gid == 0) { ((unsigned*)scal)[0] = 0u; out[0] = 0.0f; }
}

// ---------------------------------------------------------------------------
// pass_kernel<MODE, FIRST, RS>: one sweep over a (128*RS rows x 512 cols) tile
// of the pair matrix, 2 LDS col-tiles of 256 with register prefetch.
// MODE 0 (RS=1): cmax = max d2 (hi+lo dot)       -> atomicMax(uint) outScalar
// MODE 1 (RS=2): row sums of 2^(C2L*dot + b_j)   -> plain store outPart[gy][i]
//    b_j = (v_j - invC*y2_j)*log2e = FIRST ? -invC*y2_j*log2e
//                                          : LA2 - log2(sum_gy colPart[gy][j])
//    (row-norm terms cancel; re-applied identically when this row becomes a col)
// MODE 2 (RS=1): out += d2 * 2^(C2L*dot + su_i + sv_j)  -> atomicAdd outScalar
// C/D layout (m74/m101): col = lane&31, row = (reg&3) + 8*(reg>>2) + 4*(lane>>5)
// ---------------------------------------------------------------------------
template <int MODE, bool FIRST, int RS>
__global__ __launch_bounds__(256) void pass_kernel(
    const unsigned short* __restrict__ Ahi, const unsigned short* __restrict__ Alo,
    const unsigned short* __restrict__ Bhi,
    const float* __restrict__ x2row, const float* __restrict__ y2col,
    const float* __restrict__ colPart, const float* __restrict__ rowPart,
    const unsigned* __restrict__ cmaxBits,
    float* __restrict__ outPart, float* __restrict__ outScalar) {
  __shared__ short sB[256 * DIM];      // 32 KB, xor-swizzled 16B chunks
  __shared__ float sCol[256];          // per-col log-domain base (modes 1,2)
  __shared__ float sY2[256];           // modes 0,2
  __shared__ float sX2[128 * RS];      // modes 0,2
  __shared__ float sU2[128 * RS];      // mode 2
  __shared__ float sRed[4];

  const int t  = threadIdx.x;
  const int w  = t >> 6;
  const int l  = t & 63;
  const int g  = l >> 5;
  const int ln = l & 31;
  const int i0 = blockIdx.x * 128 * RS;
  const int j0 = blockIdx.y * 512;

  float invC = 0.f, C2L = 0.f;
  if constexpr (MODE != 0) {
    float cmax = __uint_as_float(*cmaxBits);
    invC = 1.0f / (0.05f * cmax);
    C2L  = 2.0f * invC * LOG2E;
  }

  // A fragments: lane holds A[m=ln][k = ks*16 + g*8 + j]
  s16x8 a_hi[RS][4], a_lo[RS][4];
#pragma unroll
  for (int s = 0; s < RS; ++s) {
    const unsigned short* pa = Ahi + (size_t)(i0 + (w * RS + s) * 32 + ln) * DIM + g * 8;
#pragma unroll
    for (int ks = 0; ks < 4; ++ks) a_hi[s][ks] = *(const s16x8*)(pa + ks * 16);
    if constexpr (MODE != 1) {
      const unsigned short* pb = Alo + (size_t)(i0 + (w * RS + s) * 32 + ln) * DIM + g * 8;
#pragma unroll
      for (int ks = 0; ks < 4; ++ks) a_lo[s][ks] = *(const s16x8*)(pb + ks * 16);
    }
  }

  auto load_tile = [&](int tile, int4* bv, float* pv, float& y2r) {
    const int4* src = (const int4*)(Bhi + (size_t)(j0 + tile * 256) * DIM);
#pragma unroll
    for (int kk = 0; kk < 8; ++kk) bv[kk] = src[t + kk * 256];
    int j = j0 + tile * 256 + t;
    if constexpr (MODE == 1) {
      if constexpr (FIRST) { pv[0] = y2col[j]; }
      else {
#pragma unroll
        for (int gy = 0; gy < 16; ++gy) pv[gy] = colPart[gy * NPTS + j];
      }
    } else if constexpr (MODE == 0) {
      y2r = y2col[j];
    } else {
      y2r = y2col[j];
#pragma unroll
      for (int gy = 0; gy < 16; ++gy) pv[gy] = colPart[gy * NPTS + j];
    }
  };

  auto store_tile = [&](const int4* bv, const float* pv, float y2r) {
#pragma unroll
    for (int kk = 0; kk < 8; ++kk) {
      int idx = t + kk * 256;
      int row = idx >> 3, c = idx & 7;
      ((int4*)sB)[row * 8 + (c ^ (row & 7))] = bv[kk];
    }
    if constexpr (MODE == 1) {
      if constexpr (FIRST) {
        sCol[t] = -invC * pv[0] * LOG2E;
      } else {
        float s = 0.f;
#pragma unroll
        for (int gy = 0; gy < 16; ++gy) s += pv[gy];
        sCol[t] = LA2 - log2_fast(s);
      }
    } else if constexpr (MODE == 0) {
      sY2[t] = y2r;
    } else {
      float s = 0.f;
#pragma unroll
      for (int gy = 0; gy < 16; ++gy) s += pv[gy];
      sCol[t] = LA2 - log2_fast(s);
      sY2[t] = y2r;
    }
  };

  int4 bv[8]; float pv[16]; float y2r = 0.f;
  load_tile(0, bv, pv, y2r);

  float racc[RS][16];
#pragma unroll
  for (int s = 0; s < RS; ++s)
#pragma unroll
    for (int r = 0; r < 16; ++r) racc[s][r] = 0.f;
  float accS = 0.f;
  float x2r[RS][16], u2r[16];

  for (int tile = 0; tile < 2; ++tile) {
    if (tile) __syncthreads();       // previous tile's compute done
    store_tile(bv, pv, y2r);
    if (tile == 0 && MODE != 1 && t < 128 * RS) {
      sX2[t] = x2row[i0 + t];
      if constexpr (MODE == 2) {
        float su = 0.f;
#pragma unroll
        for (int gy = 0; gy < 16; ++gy) su += rowPart[gy * NPTS + i0 + t];
        sU2[t] = LA2 - log2_fast(su);
      }
    }
    __syncthreads();
    if (tile == 0) {
      load_tile(1, bv, pv, y2r);     // prefetch; waited at next store_tile
      if constexpr (MODE != 1) {
#pragma unroll
        for (int s = 0; s < RS; ++s)
#pragma unroll
          for (int r = 0; r < 16; ++r) {
            int ri = (w * RS + s) * 32 + (r & 3) + 8 * (r >> 2) + 4 * g;
            x2r[s][r] = sX2[ri];
            if constexpr (MODE == 2) u2r[r] = sU2[ri];
          }
      }
    }

#pragma unroll 2
    for (int ct = 0; ct < 8; ++ct) {
      const int n = ct * 32 + ln;
      s16x8 b[4];
#pragma unroll
      for (int ks = 0; ks < 4; ++ks)
        b[ks] = *(const s16x8*)(sB + n * DIM + (((ks * 2 + g) ^ (l & 7)) * 8));

      if constexpr (MODE == 1) {
        float bb = sCol[n];
#pragma unroll
        for (int s = 0; s < RS; ++s) {
          f32x16 acc;
#pragma unroll
          for (int r = 0; r < 16; ++r) acc[r] = 0.f;
#pragma unroll
          for (int ks = 0; ks < 4; ++ks)
            acc = __builtin_amdgcn_mfma_f32_32x32x16_bf16(a_hi[s][ks], b[ks], acc, 0, 0, 0);
#pragma unroll
          for (int r = 0; r < 16; ++r)
            racc[s][r] += exp2_fast(fmaf(C2L, acc[r], bb));
        }
      } else {
        float y2v = sY2[n];
        f32x16 acc, acc2;
#pragma unroll
        for (int r = 0; r < 16; ++r) { acc[r] = 0.f; acc2[r] = 0.f; }
#pragma unroll
        for (int ks = 0; ks < 4; ++ks)
          acc = __builtin_amdgcn_mfma_f32_32x32x16_bf16(a_hi[0][ks], b[ks], acc, 0, 0, 0);
#pragma unroll
        for (int ks = 0; ks < 4; ++ks)
          acc2 = __builtin_amdgcn_mfma_f32_32x32x16_bf16(a_lo[0][ks], b[ks], acc2, 0, 0, 0);
        if constexpr (MODE == 0) {
#pragma unroll
          for (int r = 0; r < 16; ++r)
            accS = fmaxf(accS, x2r[0][r] + y2v - 2.0f * (acc[r] + acc2[r]));
        } else {
          float bb = sCol[n];
#pragma unroll
          for (int r = 0; r < 16; ++r) {
            float dot = acc[r] + acc2[r];
            float d2  = fmaxf(x2r[0][r] + y2v - 2.0f * dot, 0.0f);
            accS = fmaf(d2, exp2_fast(fmaf(C2L, dot, u2r[r] + bb)), accS);
          }
        }
      }
    }
  }

  if constexpr (MODE == 1) {
    // reduce each acc row over its 32 cols (stay within g-half), plain store
#pragma unroll
    for (int s = 0; s < RS; ++s)
#pragma unroll
      for (int r = 0; r < 16; ++r) {
        float v = racc[s][r];
        v += __shfl_xor(v, 1, 64);
        v += __shfl_xor(v, 2, 64);
        v += __shfl_xor(v, 4, 64);
        v += __shfl_xor(v, 8, 64);
        v += __shfl_xor(v, 16, 64);
        if (ln == 0)
          outPart[blockIdx.y * NPTS + i0 + (w * RS + s) * 32 +
                  (r & 3) + 8 * (r >> 2) + 4 * g] = v;
      }
  } else {
    float v = accS;
#pragma unroll
    for (int off = 1; off < 64; off <<= 1) {
      float o = __shfl_xor(v, off, 64);
      v = (MODE == 0) ? fmaxf(v, o) : (v + o);
    }
    if (l == 0) sRed[w] = v;
    __syncthreads();
    if (t == 0) {
      float r0 = (MODE == 0) ? fmaxf(fmaxf(sRed[0], sRed[1]), fmaxf(sRed[2], sRed[3]))
                             : (sRed[0] + sRed[1] + sRed[2] + sRed[3]);
      if constexpr (MODE == 0)
        atomicMax((unsigned*)outScalar, __float_as_uint(r0));
      else
        atomicAdd(outScalar, r0);
    }
  }
}

// ---------------------------------------------------------------------------
extern "C" void kernel_launch(void* const* d_in, const int* in_sizes, int n_in,
                              void* d_out, int out_size, void* d_ws, size_t ws_size,
                              hipStream_t stream) {
  (void)in_sizes; (void)n_in; (void)out_size; (void)ws_size;
  const float* XP = (const float*)d_in[0];
  const float* XQ = (const float*)d_in[1];
  float* out = (float*)d_out;

  float* ws    = (float*)d_ws;
  float* x2    = ws;                        // 8192
  float* y2    = ws + 8192;                 // 8192
  float* partU = ws + 16384;                // 16 x 8192 (row sums of u-passes)
  float* partV = partU + 16 * NPTS;         // 16 x 8192 (row sums of v-passes)
  float* scal  = partV + 16 * NPTS;         // [0] = cmax bits (16 reserved)
  unsigned short* Phi = (unsigned short*)(scal + 16);
  unsigned short* Plo = Phi + (size_t)NPTS * DIM;
  unsigned short* Qhi = Plo + (size_t)NPTS * DIM;
  unsigned short* Qlo = Qhi + (size_t)NPTS * DIM;   // total ws ~5.3 MB

  const unsigned* cmaxB = (const unsigned*)scal;

  prep_kernel<<<NPTS * 2 * DIM / 256, 256, 0, stream>>>(
      XP, XQ, Phi, Plo, Qhi, Qlo, x2, y2, scal, out);

  // Cmax (hi+lo)
  pass_kernel<0, false, 1><<<dim3(64, 16), 256, 0, stream>>>(
      Phi, Plo, Qhi, x2, y2, nullptr, nullptr, cmaxB, nullptr, scal);

  // iter 1: u-pass with v = 0 (base from y2), then v-pass from partU
  pass_kernel<1, true, 2><<<dim3(32, 16), 256, 0, stream>>>(
      Phi, nullptr, Qhi, nullptr, y2, nullptr, nullptr, cmaxB, partU, nullptr);
  pass_kernel<1, false, 2><<<dim3(32, 16), 256, 0, stream>>>(
      Qhi, nullptr, Phi, nullptr, nullptr, partU, nullptr, cmaxB, partV, nullptr);

  for (int it = 1; it < 20; ++it) {
    pass_kernel<1, false, 2><<<dim3(32, 16), 256, 0, stream>>>(
        Phi, nullptr, Qhi, nullptr, nullptr, partV, nullptr, cmaxB, partU, nullptr);
    pass_kernel<1, false, 2><<<dim3(32, 16), 256, 0, stream>>>(
        Qhi, nullptr, Phi, nullptr, nullptr, partU, nullptr, cmaxB, partV, nullptr);
  }

  // final: sum C * plan (hi+lo dot for C and plan exponent)
  pass_kernel<2, false, 1><<<dim3(64, 16), 256, 0, stream>>>(
      Phi, Plo, Qhi, x2, y2, partV, partU, cmaxB, nullptr, out);
}

// Round 4
// 869.617 us; speedup vs baseline: 8.3312x; 1.4606x over previous
//
#include <hip/hip_runtime.h>
#include <cmath>

// n = m = 8192, d = 64, reg = 0.05, 20 Sinkhorn iterations
#define NPTS 8192
#define DIM  64
#define LOG2E 1.4426950408889634f
#define LA2   -13.0f   // log2(1/8192) exactly

typedef short s16x8  __attribute__((ext_vector_type(8)));   // 8 bf16
typedef float f32x16 __attribute__((ext_vector_type(16)));  // MFMA 32x32 acc

typedef __attribute__((address_space(1))) const unsigned char g8_t;
typedef __attribute__((address_space(3))) unsigned char l8_t;

#if __has_builtin(__builtin_amdgcn_exp2f)
__device__ __forceinline__ float exp2_fast(float x) { return __builtin_amdgcn_exp2f(x); }
#else
__device__ __forceinline__ float exp2_fast(float x) { return exp2f(x); }
#endif
#if __has_builtin(__builtin_amdgcn_logf)
__device__ __forceinline__ float log2_fast(float x) { return __builtin_amdgcn_logf(x); }
#else
__device__ __forceinline__ float log2_fast(float x) { return log2f(x); }
#endif

__device__ __forceinline__ unsigned short f2bf(float x) {
  unsigned u = __float_as_uint(x);
  return (unsigned short)((u + 0x7FFFu + ((u >> 16) & 1u)) >> 16);
}
__device__ __forceinline__ float bf2f(unsigned short b) {
  return __uint_as_float(((unsigned)b) << 16);
}

// ---------------------------------------------------------------------------
// prep: bf16 hi/lo split + squared row norms; init scal/out. one wave per row.
// ---------------------------------------------------------------------------
__global__ __launch_bounds__(256) void prep_kernel(
    const float* __restrict__ XP, const float* __restrict__ XQ,
    unsigned short* __restrict__ Phi, unsigned short* __restrict__ Plo,
    unsigned short* __restrict__ Qhi, unsigned short* __restrict__ Qlo,
    float* __restrict__ x2, float* __restrict__ y2,
    float* __restrict__ scal, float* __restrict__ out) {
  int gid  = blockIdx.x * 256 + threadIdx.x;
  int lane = threadIdx.x & 63;
  int row  = gid >> 6;            // 0..16383: P rows then Q rows (wave-uniform)
  int isP  = row < NPTS;
  int r    = row & (NPTS - 1);
  const float* X = isP ? XP : XQ;
  float x = X[r * DIM + lane];
  unsigned short h = f2bf(x);
  (isP ? Phi : Qhi)[r * DIM + lane] = h;
  (isP ? Plo : Qlo)[r * DIM + lane] = f2bf(x - bf2f(h));
  float s = x * x;
  for (int off = 32; off; off >>= 1) s += __shfl_down(s, off, 64);
  if (lane == 0) (isP ? x2 : y2)[r] = s;
  if (gid == 0) { ((unsigned*)scal)[0] = 0u; out[0] = 0.0f; }
}

// ---------------------------------------------------------------------------
// pass_kernel<MODE, FIRST, MINW>: sweep a (128 rows x 512 cols) tile of the
// pair matrix; B panel staged in LDS via async global_load_lds, two 256-col
// halves in one 32 KB buffer. Col bases for all 512 cols computed up front.
// MODE 0: cmax = max d2 (hi dot)                 -> atomicMax(uint) outScalar
// MODE 1: row sums of 2^(C2L*dot + b_j)          -> plain store outPart[gy][i]
//    b_j = FIRST ? -invC*y2_j*log2e : LA2 - log2(sum_gy colPart[gy][j])
//    (row-norm terms cancel exactly: u_i - invC*x2_i = LA2 - log2(rowsum_i))
// MODE 2: out += d2 * 2^(C2L*dot + bu_i + bv_j)  -> atomicAdd outScalar
// C/D layout (m74/m101): col = lane&31, row = (reg&3) + 8*(reg>>2) + 4*(lane>>5)
// ---------------------------------------------------------------------------
template <int MODE, bool FIRST, int MINW>
__global__ __launch_bounds__(256, MINW) void pass_kernel(
    const unsigned short* __restrict__ Ahi, const unsigned short* __restrict__ Alo,
    const unsigned short* __restrict__ Bhi,
    const float* __restrict__ x2row, const float* __restrict__ y2col,
    const float* __restrict__ colPart, const float* __restrict__ rowPart,
    const unsigned* __restrict__ cmaxBits,
    float* __restrict__ outPart, float* __restrict__ outScalar) {
  __shared__ short sB[256 * DIM];   // 32 KB current half-panel, xor-swizzled
  __shared__ float sCol[512];       // per-col log2-domain base (modes 1,2)
  __shared__ float sY2[512];        // modes 0,2
  __shared__ float sX2[128];        // modes 0,2
  __shared__ float sU2[128];        // mode 2
  __shared__ float sRed[4];

  const int t  = threadIdx.x;
  const int w  = t >> 6;
  const int l  = t & 63;
  const int g  = l >> 5;
  const int ln = l & 31;
  const int i0 = blockIdx.x * 128;
  const int j0 = blockIdx.y * 512;

  float invC = 0.f, C2L = 0.f;
  if constexpr (MODE != 0) {
    float cmax = __uint_as_float(*cmaxBits);
    invC = 1.0f / (0.05f * cmax);
    C2L  = 2.0f * invC * LOG2E;
  }

  // per-lane global source for async staging: physical slot s = w*512+c*64+l
  // holds (row = s>>3, chunk = (s&7)^(row&7)); +64 slots = +1024 B exactly.
  const unsigned char* gB = (const unsigned char*)(Bhi + (size_t)j0 * DIM);
  const unsigned char* gsrc0;
  {
    int s   = w * 512 + l;
    int row = s >> 3;
    int cc  = (s & 7) ^ (row & 7);
    gsrc0 = gB + row * 128 + cc * 16;
  }
  auto stage = [&](int half) {
    const unsigned char* g0 = gsrc0 + half * 32768;
#pragma unroll
    for (int c = 0; c < 8; ++c)
      __builtin_amdgcn_global_load_lds(
          (g8_t*)(g0 + c * 1024),
          (l8_t*)((unsigned char*)sB + w * 8192 + c * 1024), 16, 0, 0);
  };

  // A fragments: lane holds A[m=ln][k = ks*16 + g*8 + j]
  s16x8 a_hi[4], a_lo[4];
  {
    const unsigned short* pa = Ahi + (size_t)(i0 + w * 32 + ln) * DIM + g * 8;
#pragma unroll
    for (int ks = 0; ks < 4; ++ks) a_hi[ks] = *(const s16x8*)(pa + ks * 16);
    if constexpr (MODE == 2) {
      const unsigned short* pb = Alo + (size_t)(i0 + w * 32 + ln) * DIM + g * 8;
#pragma unroll
      for (int ks = 0; ks < 4; ++ks) a_lo[ks] = *(const s16x8*)(pb + ks * 16);
    }
  }

  stage(0);

  // whole-panel column bases / norms (computed once)
#pragma unroll
  for (int c0 = 0; c0 < 2; ++c0) {
    int c = c0 * 256 + t;
    int j = j0 + c;
    if constexpr (MODE == 0) {
      sY2[c] = y2col[j];
    } else if constexpr (MODE == 1) {
      if constexpr (FIRST) {
        sCol[c] = -invC * y2col[j] * LOG2E;
      } else {
        float s = 0.f;
#pragma unroll
        for (int gy = 0; gy < 16; ++gy) s += colPart[gy * NPTS + j];
        sCol[c] = LA2 - log2_fast(s);
      }
    } else {
      float s = 0.f;
#pragma unroll
      for (int gy = 0; gy < 16; ++gy) s += colPart[gy * NPTS + j];
      sCol[c] = LA2 - log2_fast(s);
      sY2[c] = y2col[j];
    }
  }
  if constexpr (MODE != 1) {
    if (t < 128) {
      sX2[t] = x2row[i0 + t];
      if constexpr (MODE == 2) {
        float s = 0.f;
#pragma unroll
        for (int gy = 0; gy < 16; ++gy) s += rowPart[gy * NPTS + i0 + t];
        sU2[t] = LA2 - log2_fast(s);
      }
    }
  }
  __syncthreads();   // drains the async stage too (vmcnt at barrier)

  float x2r[16], u2r[16];
  if constexpr (MODE != 1) {
#pragma unroll
    for (int r = 0; r < 16; ++r) {
      int ri = w * 32 + (r & 3) + 8 * (r >> 2) + 4 * g;
      x2r[r] = sX2[ri];
      if constexpr (MODE == 2) u2r[r] = sU2[ri];
    }
  }

  float racc[16];
#pragma unroll
  for (int r = 0; r < 16; ++r) racc[r] = 0.f;
  float accS = 0.f;

  for (int half = 0; half < 2; ++half) {
    if (half) {                       // restage second 256-col half
      __syncthreads();
      stage(1);
      __syncthreads();
    }
#pragma unroll 2
    for (int ct = 0; ct < 8; ++ct) {
      const int nn = ct * 32 + ln;    // row within current sB tile
      const int n  = half * 256 + nn; // panel column index
      s16x8 b[4];
#pragma unroll
      for (int ks = 0; ks < 4; ++ks)
        b[ks] = *(const s16x8*)(sB + nn * DIM + (((ks * 2 + g) ^ (ln & 7)) * 8));
      f32x16 acc;
#pragma unroll
      for (int r = 0; r < 16; ++r) acc[r] = 0.f;
#pragma unroll
      for (int ks = 0; ks < 4; ++ks)
        acc = __builtin_amdgcn_mfma_f32_32x32x16_bf16(a_hi[ks], b[ks], acc, 0, 0, 0);

      if constexpr (MODE == 1) {
        float bb = sCol[n];
#pragma unroll
        for (int r = 0; r < 16; ++r)
          racc[r] += exp2_fast(fmaf(C2L, acc[r], bb));
      } else if constexpr (MODE == 0) {
        float y2v = sY2[n];
#pragma unroll
        for (int r = 0; r < 16; ++r)
          accS = fmaxf(accS, fmaf(-2.0f, acc[r], x2r[r] + y2v));
      } else {
        f32x16 acc2;
#pragma unroll
        for (int r = 0; r < 16; ++r) acc2[r] = 0.f;
#pragma unroll
        for (int ks = 0; ks < 4; ++ks)
          acc2 = __builtin_amdgcn_mfma_f32_32x32x16_bf16(a_lo[ks], b[ks], acc2, 0, 0, 0);
        float y2v = sY2[n];
        float bb  = sCol[n];
#pragma unroll
        for (int r = 0; r < 16; ++r) {
          float dot = acc[r] + acc2[r];
          float d2  = fmaxf(fmaf(-2.0f, dot, x2r[r] + y2v), 0.0f);
          accS = fmaf(d2, exp2_fast(fmaf(C2L, dot, u2r[r] + bb)), accS);
        }
      }
    }
  }

  if constexpr (MODE == 1) {
    // reduce each acc row over its 32 cols (stays within the g-half), store
#pragma unroll
    for (int r = 0; r < 16; ++r) {
      float v = racc[r];
      v += __shfl_xor(v, 1, 64);
      v += __shfl_xor(v, 2, 64);
      v += __shfl_xor(v, 4, 64);
      v += __shfl_xor(v, 8, 64);
      v += __shfl_xor(v, 16, 64);
      if (ln == 0)
        outPart[blockIdx.y * NPTS + i0 + w * 32 +
                (r & 3) + 8 * (r >> 2) + 4 * g] = v;
    }
  } else {
    float v = accS;
#pragma unroll
    for (int off = 1; off < 64; off <<= 1) {
      float o = __shfl_xor(v, off, 64);
      v = (MODE == 0) ? fmaxf(v, o) : (v + o);
    }
    if (l == 0) sRed[w] = v;
    __syncthreads();
    if (t == 0) {
      float r0 = (MODE == 0) ? fmaxf(fmaxf(sRed[0], sRed[1]), fmaxf(sRed[2], sRed[3]))
                             : (sRed[0] + sRed[1] + sRed[2] + sRed[3]);
      if constexpr (MODE == 0)
        atomicMax((unsigned*)outScalar, __float_as_uint(r0));
      else
        atomicAdd(outScalar, r0);
    }
  }
}

// ---------------------------------------------------------------------------
extern "C" void kernel_launch(void* const* d_in, const int* in_sizes, int n_in,
                              void* d_out, int out_size, void* d_ws, size_t ws_size,
                              hipStream_t stream) {
  (void)in_sizes; (void)n_in; (void)out_size; (void)ws_size;
  const float* XP = (const float*)d_in[0];
  const float* XQ = (const float*)d_in[1];
  float* out = (float*)d_out;

  float* ws    = (float*)d_ws;
  float* x2    = ws;                        // 8192
  float* y2    = ws + 8192;                 // 8192
  float* partU = ws + 16384;                // 16 x 8192 (u-pass row sums)
  float* partV = partU + 16 * NPTS;         // 16 x 8192 (v-pass row sums)
  float* scal  = partV + 16 * NPTS;         // [0] = cmax bits (16 reserved)
  unsigned short* Phi = (unsigned short*)(scal + 16);
  unsigned short* Plo = Phi + (size_t)NPTS * DIM;
  unsigned short* Qhi = Plo + (size_t)NPTS * DIM;
  unsigned short* Qlo = Qhi + (size_t)NPTS * DIM;   // total ws ~5.3 MB

  const unsigned* cmaxB = (const unsigned*)scal;
  dim3 grid(NPTS / 128, NPTS / 512);        // (64, 16) = 1024 blocks

  prep_kernel<<<NPTS * 2 * DIM / 256, 256, 0, stream>>>(
      XP, XQ, Phi, Plo, Qhi, Qlo, x2, y2, scal, out);

  // Cmax (hi-only: |err| ~1e-4 relative, shifts effective reg negligibly)
  pass_kernel<0, false, 4><<<grid, 256, 0, stream>>>(
      Phi, nullptr, Qhi, x2, y2, nullptr, nullptr, cmaxB, nullptr, scal);

  // iter 1: u-pass with v = 0 (base from y2), then v-pass from partU
  pass_kernel<1, true, 4><<<grid, 256, 0, stream>>>(
      Phi, nullptr, Qhi, nullptr, y2, nullptr, nullptr, cmaxB, partU, nullptr);
  pass_kernel<1, false, 4><<<grid, 256, 0, stream>>>(
      Qhi, nullptr, Phi, nullptr, nullptr, partU, nullptr, cmaxB, partV, nullptr);

  for (int it = 1; it < 20; ++it) {
    pass_kernel<1, false, 4><<<grid, 256, 0, stream>>>(
        Phi, nullptr, Qhi, nullptr, nullptr, partV, nullptr, cmaxB, partU, nullptr);
    pass_kernel<1, false, 4><<<grid, 256, 0, stream>>>(
        Qhi, nullptr, Phi, nullptr, nullptr, partU, nullptr, cmaxB, partV, nullptr);
  }

  // final: sum C * plan (hi+lo dot for C accuracy)
  pass_kernel<2, false, 2><<<grid, 256, 0, stream>>>(
      Phi, Plo, Qhi, x2, y2, partV, partU, cmaxB, nullptr, out);
}